// Round 1
// baseline (502.924 us; speedup 1.0000x reference)
//
#include <hip/hip_runtime.h>

#define Ff 16
#define Kk 8
#define SIZEk 64
#define PDd 256
#define EDd 768
#define Nn 197
#define BZz 512          // B*F
#define NPROD 64         // producer (keys/KW/ksim) blocks
#define RB  256          // route blocks (2 bz each)
#define ED4 192          // 768/4
#define PD4 64           // 256/4
#define OUT_LOSS ((size_t)32 * 128 * EDd)   // 3145728: ps_loss slot in d_out
#define LOSS_SCALE (1.0f / 32.0f)           // F/BZ = 16/512
#define MAGIC 0x5A17EC0Du                   // != 0xAAAAAAAA poison, != 0

__device__ __forceinline__ void acc4(float4& s, float4 a) {
    s.x += a.x; s.y += a.y; s.z += a.z; s.w += a.w;
}

// One kernel. Blocks 0..63 (producers): keys[s]=l2norm(pv[s]); KW[s]=keys[s]@Wout^T;
// publish slot[s]=MAGIC (release, agent scope); then ksim row s after acquiring all
// slots. Blocks 64..319 (route, 2 bz each): mean -> query run before the dependency;
// acquire all 64 slots just before top-8. Producer work hides under the HBM read
// phase; expected spin time ~0. launch_bounds(256,2) => >=2 blocks/CU => all 320
// blocks co-resident => no spin deadlock.
//
// Phase-1 v2: all 4 waves issue x loads (384 f4-columns -> 1 col/thread for all 256
// threads + 2nd col for threads 0..127; wave-uniform predicate) and the n-loop is
// unrolled 8-deep => ~48 KB outstanding per CU (was ~24 KB on 3 waves) => the read
// phase tolerates ~2 us loaded HBM latency instead of ~1 us.
__global__ __launch_bounds__(256, 2) void k_all(const float4* __restrict__ x,
                                                const float* __restrict__ Win,
                                                const float* __restrict__ Wout,
                                                const float* __restrict__ pv,
                                                float* __restrict__ keys,
                                                float* __restrict__ KW,
                                                unsigned* __restrict__ slots,
                                                float* __restrict__ out) {
    int blk = blockIdx.x, t = threadIdx.x;

    if (blk < NPROD) {
        // ================= producer block s =================
        __shared__ float ks[PDd];
        __shared__ float redp[4];
        __shared__ float s_norm;
        int s = blk;
        float v  = pv[(size_t)s * PDd + t];
        float sq = v * v;
        for (int o = 32; o > 0; o >>= 1) sq += __shfl_down(sq, o);
        if ((t & 63) == 0) redp[t >> 6] = sq;
        __syncthreads();
        if (t == 0) s_norm = fmaxf(sqrtf(redp[0] + redp[1] + redp[2] + redp[3]), 1e-12f);
        __syncthreads();
        float kv = v / s_norm;
        ks[t] = kv;
        keys[(size_t)s * PDd + t] = kv;
        __syncthreads();

        // KW row s: 768 outputs, 3 per thread
        for (int r = 0; r < 3; r++) {
            int e = t + 256 * r;
            const float4* w  = (const float4*)(Wout + (size_t)e * PDd);
            const float4* k4 = (const float4*)ks;
            float d = 0.f;
            for (int i = 0; i < PD4; i++) {
                float4 wv = w[i]; float4 kvv = k4[i];
                d += wv.x * kvv.x + wv.y * kvv.y + wv.z * kvv.z + wv.w * kvv.w;
            }
            KW[(size_t)s * EDd + e] = d;
        }
        if (s == 0 && t == 0) out[OUT_LOSS] = 0.0f;   // ordered before slot-0 release
        __syncthreads();   // compiler emits vmcnt(0) drain before barrier: all stores in L2
        if (t == 0)
            __hip_atomic_store(&slots[s], MAGIC, __ATOMIC_RELEASE, __HIP_MEMORY_SCOPE_AGENT);

        // ---- ksim row s (needs ALL keys) ----
        if (t < SIZEk) {
            while (__hip_atomic_load(&slots[t], __ATOMIC_ACQUIRE, __HIP_MEMORY_SCOPE_AGENT)
                   != MAGIC)
                __builtin_amdgcn_s_sleep(8);
        }
        __syncthreads();
        if (t < SIZEk) {
            const float4* a = (const float4*)(keys + (size_t)s * PDd);
            const float4* b = (const float4*)(keys + (size_t)t * PDd);
            float d = 0.f;
            for (int c = 0; c < PD4; c++) {
                float4 av = a[c], bv = b[c];
                d += av.x * bv.x + av.y * bv.y + av.z * bv.z + av.w * bv.w;
            }
            float vv = fabsf(d - (s == t ? 1.0f : 0.0f));
            for (int o = 32; o > 0; o >>= 1) vv += __shfl_down(vv, o);
            if (t == 0) atomicAdd(out + OUT_LOSS, vv * LOSS_SCALE);
        }
        return;
    }

    // ================= route block: bz pair {2b, 2b+1} =================
    __shared__ float xs[2][EDd];     // xf for both rows (as 192 float4 each)
    __shared__ float qs[2][PDd];     // normalized query rows
    __shared__ int   s_idx[2][Kk];
    __shared__ float s_sim[2][Kk];
    __shared__ float red[2][4];
    int bz0 = (blk - NPROD) * 2;

    // ---- phase 1: frame means. 384 f4-columns: item A = col t (rows split
    //      192/64), item B = row1 col 64+t for threads 0..127. All 4 waves load. --
    {
        const float4* b0 = x + (size_t)bz0 * Nn * ED4;
        const float4* b1 = b0 + (size_t)Nn * ED4;
        const int  rA = (t < ED4) ? 0 : 1;
        const int  cA = (t < ED4) ? t : (t - ED4);
        const float4* pA = (rA ? b1 : b0) + cA;
        const bool hasB = (t < 128);                 // wave-uniform (waves 0,1)
        const int  cB   = 64 + (t & 127);            // row 1, cols 64..191
        const float4* pB = b1 + cB;
        float4 sA = make_float4(0.f, 0.f, 0.f, 0.f);
        float4 sB = make_float4(0.f, 0.f, 0.f, 0.f);
        int n = 0;
        if (hasB) {
            for (; n + 8 <= Nn; n += 8) {            // 16 float4 in flight
                float4 a0 = pA[(n + 0) * ED4], a1 = pA[(n + 1) * ED4];
                float4 a2 = pA[(n + 2) * ED4], a3 = pA[(n + 3) * ED4];
                float4 a4 = pA[(n + 4) * ED4], a5 = pA[(n + 5) * ED4];
                float4 a6 = pA[(n + 6) * ED4], a7 = pA[(n + 7) * ED4];
                float4 q0 = pB[(n + 0) * ED4], q1 = pB[(n + 1) * ED4];
                float4 q2 = pB[(n + 2) * ED4], q3 = pB[(n + 3) * ED4];
                float4 q4 = pB[(n + 4) * ED4], q5 = pB[(n + 5) * ED4];
                float4 q6 = pB[(n + 6) * ED4], q7 = pB[(n + 7) * ED4];
                acc4(sA, a0); acc4(sA, a1); acc4(sA, a2); acc4(sA, a3);
                acc4(sA, a4); acc4(sA, a5); acc4(sA, a6); acc4(sA, a7);
                acc4(sB, q0); acc4(sB, q1); acc4(sB, q2); acc4(sB, q3);
                acc4(sB, q4); acc4(sB, q5); acc4(sB, q6); acc4(sB, q7);
            }
            for (; n < Nn; n++) { acc4(sA, pA[n * ED4]); acc4(sB, pB[n * ED4]); }
        } else {
            for (; n + 8 <= Nn; n += 8) {            // 8 float4 in flight
                float4 a0 = pA[(n + 0) * ED4], a1 = pA[(n + 1) * ED4];
                float4 a2 = pA[(n + 2) * ED4], a3 = pA[(n + 3) * ED4];
                float4 a4 = pA[(n + 4) * ED4], a5 = pA[(n + 5) * ED4];
                float4 a6 = pA[(n + 6) * ED4], a7 = pA[(n + 7) * ED4];
                acc4(sA, a0); acc4(sA, a1); acc4(sA, a2); acc4(sA, a3);
                acc4(sA, a4); acc4(sA, a5); acc4(sA, a6); acc4(sA, a7);
            }
            for (; n < Nn; n++) acc4(sA, pA[n * ED4]);
        }
        const float inv = 1.0f / (float)Nn;
        ((float4*)xs[rA])[cA] = make_float4(sA.x * inv, sA.y * inv, sA.z * inv, sA.w * inv);
        if (hasB)
            ((float4*)xs[1])[cB] = make_float4(sB.x * inv, sB.y * inv, sB.z * inv, sB.w * inv);
    }
    __syncthreads();

    // ---- phase 2: query p=t for both rows (one W_in read, two dots) ----
    {
        const float4* w  = (const float4*)Win + (size_t)t * ED4;
        const float4* x0 = (const float4*)xs[0];
        const float4* x1 = (const float4*)xs[1];
        float d0a = 0.f, d0b = 0.f, d1a = 0.f, d1b = 0.f;
        for (int i = 0; i < ED4; i += 2) {           // split accumulators: 2 chains
            float4 w0 = w[i],     w1 = w[i + 1];
            float4 u0 = x0[i],    u1 = x1[i];
            float4 u2 = x0[i + 1], u3 = x1[i + 1];
            d0a += w0.x * u0.x + w0.y * u0.y + w0.z * u0.z + w0.w * u0.w;
            d1a += w0.x * u1.x + w0.y * u1.y + w0.z * u1.z + w0.w * u1.w;
            d0b += w1.x * u2.x + w1.y * u2.y + w1.z * u2.z + w1.w * u2.w;
            d1b += w1.x * u3.x + w1.y * u3.y + w1.z * u3.z + w1.w * u3.w;
        }
        float d0 = d0a + d0b, d1 = d1a + d1b;
        float sq0 = d0 * d0, sq1 = d1 * d1;
        for (int o = 32; o > 0; o >>= 1) {
            sq0 += __shfl_down(sq0, o);
            sq1 += __shfl_down(sq1, o);
        }
        if ((t & 63) == 0) { red[0][t >> 6] = sq0; red[1][t >> 6] = sq1; }
        __syncthreads();
        float n0 = fmaxf(sqrtf(red[0][0] + red[0][1] + red[0][2] + red[0][3]), 1e-12f);
        float n1 = fmaxf(sqrtf(red[1][0] + red[1][1] + red[1][2] + red[1][3]), 1e-12f);
        qs[0][t] = d0 / n0;
        qs[1][t] = d1 / n1;
    }

    // ---- acquire keys/KW (threads 0..63 poll one slot each; ~0 spin expected) --
    if (t < SIZEk) {
        while (__hip_atomic_load(&slots[t], __ATOMIC_ACQUIRE, __HIP_MEMORY_SCOPE_AGENT)
               != MAGIC)
            __builtin_amdgcn_s_sleep(8);
    }
    __syncthreads();

    // ---- phase 3: sim + top-8; wave 0 -> row 0, wave 1 -> row 1 ----
    if (t < 2 * SIZEk) {
        int row  = t >> 6;           // wave id
        int lane = t & 63;
        const float4* kr = (const float4*)(keys + (size_t)lane * PDd);
        const float4* qr = (const float4*)qs[row];
        float d = 0.f;
        for (int c = 0; c < PD4; c++) {
            float4 a = kr[c], b = qr[c];
            d += a.x * b.x + a.y * b.y + a.z * b.z + a.w * b.w;
        }
        float v = d;
        for (int k = 0; k < Kk; k++) {
            float mv = v; int mi = lane;
            for (int o = 32; o > 0; o >>= 1) {
                float ov = __shfl_xor(mv, o);
                int   oi = __shfl_xor(mi, o);
                if (ov > mv || (ov == mv && oi < mi)) { mv = ov; mi = oi; }
            }
            if (lane == 0) { s_idx[row][k] = mi; s_sim[row][k] = mv; }
            if (lane == mi) v = -3e38f;  // remove winner (tie -> lowest idx, like lax.top_k)
        }
    }
    __syncthreads();

    // ---- phase 4: recon + diff for both rows (thread t == d) ----
    {
        float r0 = 0.f, r1 = 0.f;
        for (int k = 0; k < Kk; k++) {
            r0 += s_sim[0][k] * keys[(size_t)s_idx[0][k] * PDd + t];
            r1 += s_sim[1][k] * keys[(size_t)s_idx[1][k] * PDd + t];
        }
        float e0 = r0 - qs[0][t];
        float e1 = r1 - qs[1][t];
        float sq = e0 * e0 + e1 * e1;
        for (int o = 32; o > 0; o >>= 1) sq += __shfl_down(sq, o);
        if ((t & 63) == 0) red[0][t >> 6] = sq;
        __syncthreads();
        if (t == 0) atomicAdd(out + OUT_LOSS,
                              (red[0][0] + red[0][1] + red[0][2] + red[0][3]) * LOSS_SCALE);
    }

    // ---- phase 5: 16 contiguous out rows (bz0*K .. bz0*K+15) = KW[idx] gather --
    float4* orow = (float4*)out + (size_t)bz0 * Kk * ED4;
    for (int i = t; i < 2 * Kk * ED4; i += 256) {
        int which = i / ED4;         // 0..15
        int e4    = i - which * ED4;
        int idx   = s_idx[which >> 3][which & 7];
        orow[i] = ((const float4*)(KW + (size_t)idx * EDd))[e4];
    }
}

extern "C" void kernel_launch(void* const* d_in, const int* in_sizes, int n_in,
                              void* d_out, int out_size, void* d_ws, size_t ws_size,
                              hipStream_t stream) {
    const float* x    = (const float*)d_in[0];   // [32, 16*197, 768]
    const float* Win  = (const float*)d_in[1];   // [256, 768]
    const float* Wout = (const float*)d_in[2];   // [768, 256]
    const float* pv   = (const float*)d_in[3];   // [64, 1, 256]
    float* out = (float*)d_out;                  // [32,128,768] ++ [1]
    float* ws  = (float*)d_ws;

    float*    keys  = ws;                        // 64*256 = 16384 floats
    float*    KW    = ws + 16384;                // 64*768 = 49152 floats
    unsigned* slots = (unsigned*)(ws + 65536);   // 64 flags (poisoned != MAGIC each launch)

    k_all<<<NPROD + RB, 256, 0, stream>>>((const float4*)x, Win, Wout, pv,
                                          keys, KW, slots, out);
}